// Round 8
// baseline (766.507 us; speedup 1.0000x reference)
//
#include <hip/hip_runtime.h>
#include <cstdint>
#include <cstddef>

typedef unsigned short u16;
typedef __bf16 bf16x8 __attribute__((ext_vector_type(8)));
typedef float f32x4 __attribute__((ext_vector_type(4)));

#define KOFF 27
#define EPSBN 1e-5f

__device__ inline u16 f2bf(float f) {
  unsigned int u = __float_as_uint(f);
  unsigned int r = (u + 0x7FFFu + ((u >> 16) & 1u)) >> 16;  // RNE
  return (u16)r;
}
__device__ inline float bf2f(u16 h) {
  return __uint_as_float(((unsigned int)h) << 16);
}

// ---------------- fused prep kernel ----------------
// blocks [0,G): pack neighbor table into per-wave int4 layout
//   nbrP[(k*G + g)*16 + l] = int4{ nbr[g*64+l][k], nbr[g*64+l+16][k],
//                                  nbr[g*64+l+32][k], nbr[g*64+l+48][k] }
//   plane k=27 = all -1 (padding so the k+1 prefetch at k=26 stays in-bounds).
// blocks [G, G+gW): pack W1 into MFMA B-frag order (bf16)
// blocks [G+gW, G+2gW): pack W2
// blocks [G+2gW, ...): cast feats->bf16 (first block also zeroes stats[256])
__global__ void k_prep(const float* __restrict__ feats, const float* __restrict__ W1,
                       const float* __restrict__ W2, const int* __restrict__ nbr,
                       u16* __restrict__ featsb, u16* __restrict__ w1p,
                       u16* __restrict__ w2p, int4* __restrict__ nbrP,
                       float* __restrict__ stats, int N, int G, int gW, int n4) {
  __shared__ int L[64 * KOFF];
  const int t = threadIdx.x;
  const int bid = blockIdx.x;

  if (bid < G) {  // neighbor pack
    const int g = bid;
    const int v0 = g * 64;
    for (int i = t; i < 64 * KOFF; i += 256) {
      const int v = v0 + i / KOFF;
      L[i] = (v < N) ? nbr[(size_t)v * KOFF + i % KOFF] : -1;
    }
    __syncthreads();
    for (int i = t; i < KOFF * 16; i += 256) {
      const int k = i >> 4, l = i & 15;
      int4 val;
      val.x = L[l * KOFF + k];
      val.y = L[(l + 16) * KOFF + k];
      val.z = L[(l + 32) * KOFF + k];
      val.w = L[(l + 48) * KOFF + k];
      nbrP[((size_t)k * G + g) * 16 + l] = val;
    }
    if (t < 16) nbrP[((size_t)KOFF * G + g) * 16 + t] = make_int4(-1, -1, -1, -1);
    return;
  }
  if (bid < G + 2 * gW) {  // weight pack
    const int wi = bid - G;
    const bool second = wi >= gW;
    const float* W = second ? W2 : W1;
    u16* Wp = second ? w2p : w1p;
    const int tid = (second ? wi - gW : wi) * 256 + t;
    if (tid >= KOFF * 4096) return;
    const int k = tid >> 12;
    const int rem = tid & 4095;
    const int slot = rem >> 3;
    const int e = rem & 7;
    const int ks = slot >> 8;
    const int ct = (slot >> 6) & 3;
    const int lane = slot & 63;
    const int j = ks * 32 + ((lane >> 4) << 3) + e;
    const int c = ct * 16 + (lane & 15);
    Wp[tid] = f2bf(W[(k * 64 + j) * 64 + c]);
    return;
  }
  // feats cast
  const int idx = bid - G - 2 * gW;
  if (idx == 0) stats[t] = 0.f;
  const int i = idx * 256 + t;
  if (i >= n4) return;
  const float4 v = reinterpret_cast<const float4*>(feats)[i];
  ushort4 o;
  o.x = f2bf(v.x); o.y = f2bf(v.y); o.z = f2bf(v.z); o.w = f2bf(v.w);
  reinterpret_cast<ushort4*>(featsb)[i] = o;
}

// ---------------- conv kernel (R2 structure, verified deltas only) ----------------
// Block 256 = 4 waves; each wave owns 64 voxels (group g) x all 64 out channels.
// Barrier-free, compiler-scheduled main loop (best measured structure, R2=95us).
// Deltas vs R2: launch_bounds(256,4) (same VGPR=60, +1 wave/SIMD), XCD swizzle
// (FETCH-verified), int4-packed neighbor ids (1 dwordx4 instead of 4 scalar).
// NO setprio, NO refill interleave, NO barriers (all measured regressions).
__launch_bounds__(256, 4)
__global__ void k_conv(const u16* __restrict__ F, const u16* __restrict__ Wp,
                       const int4* __restrict__ nbrP, float* __restrict__ out,
                       float* __restrict__ stats, int N, int G) {
  __shared__ float sred[4][128];
  const int t = threadIdx.x;
  const int w = t >> 6;
  const int lane = t & 63;

  // bijective XCD-aware block swizzle (m204 form)
  const int nwg = gridDim.x, bid = blockIdx.x;
  const int q = nwg >> 3, r = nwg & 7;
  const int xcd = bid & 7, o = bid >> 3;
  const int wg = (xcd < r ? xcd * (q + 1) : r * (q + 1) + (xcd - r) * q) + o;

  const int g = wg * 4 + w;              // this wave's 64-voxel group
  const int ch = (lane >> 4) << 3;       // A-frag channel offset (u16 units)
  const size_t G16 = (size_t)G * 16;     // int4 stride per k-plane
  const int4* nb = nbrP + (size_t)g * 16 + (lane & 15);

  f32x4 acc[4][4];
#pragma unroll
  for (int m = 0; m < 4; ++m)
#pragma unroll
    for (int c = 0; c < 4; ++c) acc[m][c] = (f32x4){0.f, 0.f, 0.f, 0.f};

  int4 idv = nb[0];  // ids for k=0
  const u16* bp = Wp + (lane << 3);

#pragma unroll 3
  for (int k = 0; k < KOFF; ++k) {
    // B fragments for this k (broadcast across waves -> L1 hits)
    bf16x8 bfr[2][4];
#pragma unroll
    for (int ks = 0; ks < 2; ++ks)
#pragma unroll
      for (int c = 0; c < 4; ++c)
        bfr[ks][c] = *reinterpret_cast<const bf16x8*>(bp + ((size_t)k << 12) + (ks << 11) + (c << 9));

    // A fragments: direct register gather (guarded, zero-init)
    const int ids[4] = {idv.x, idv.y, idv.z, idv.w};
    bf16x8 a0[4], a1[4];
#pragma unroll
    for (int m = 0; m < 4; ++m) {
      a0[m] = (bf16x8){};
      a1[m] = (bf16x8){};
      if (ids[m] >= 0) {
        const u16* fr = F + ((size_t)(unsigned)ids[m] << 6) + ch;
        a0[m] = *reinterpret_cast<const bf16x8*>(fr);
        a1[m] = *reinterpret_cast<const bf16x8*>(fr + 32);
      }
    }

    // prefetch next k's ids: one dwordx4 (plane 27 = -1 padding)
    idv = nb[(size_t)(k + 1) * G16];

#pragma unroll
    for (int m = 0; m < 4; ++m)
#pragma unroll
      for (int c = 0; c < 4; ++c)
        acc[m][c] = __builtin_amdgcn_mfma_f32_16x16x32_bf16(a0[m], bfr[0][c], acc[m][c], 0, 0, 0);
#pragma unroll
    for (int m = 0; m < 4; ++m)
#pragma unroll
      for (int c = 0; c < 4; ++c)
        acc[m][c] = __builtin_amdgcn_mfma_f32_16x16x32_bf16(a1[m], bfr[1][c], acc[m][c], 0, 0, 0);
  }

  // ---- store f32 + fused BN-stat partial reduction ----
  const int row0 = g * 64 + ((lane >> 4) << 2);
#pragma unroll
  for (int m = 0; m < 4; ++m) {
#pragma unroll
    for (int c = 0; c < 4; ++c) {
      const int col = (c << 4) + (lane & 15);
#pragma unroll
      for (int e = 0; e < 4; ++e) {
        const int v = row0 + (m << 4) + e;
        if (v < N) out[((size_t)v << 6) + col] = acc[m][c][e];
      }
    }
  }

#pragma unroll
  for (int c = 0; c < 4; ++c) {
    float s = 0.f, qq = 0.f;
#pragma unroll
    for (int m = 0; m < 4; ++m)
#pragma unroll
      for (int e = 0; e < 4; ++e) {
        const float x = acc[m][c][e];  // OOB rows contribute exact 0
        s += x;
        qq += x * x;
      }
    s += __shfl_xor(s, 16, 64);
    s += __shfl_xor(s, 32, 64);
    qq += __shfl_xor(qq, 16, 64);
    qq += __shfl_xor(qq, 32, 64);
    if (lane < 16) {
      sred[w][(c << 4) + lane] = s;
      sred[w][64 + (c << 4) + lane] = qq;
    }
  }
  __syncthreads();
  if (t < 128) {
    const float tot = sred[0][t] + sred[1][t] + sred[2][t] + sred[3][t];
    atomicAdd(&stats[t], tot);
  }
}

// ---------------- BN finalize / apply ----------------

__global__ void k_final(const float* __restrict__ stats, const float* __restrict__ gamma,
                        const float* __restrict__ beta, float* __restrict__ sb, int N) {
  const int c = threadIdx.x;  // 64
  const float inv = 1.0f / (float)N;
  const float mu = stats[c] * inv;
  const float var = stats[64 + c] * inv - mu * mu;
  const float sc = gamma[c] * rsqrtf(var + EPSBN);
  sb[c] = sc;
  sb[64 + c] = beta[c] - mu * sc;
}

// y = relu(x*sc+bi) -> bf16 x_net
__global__ void k_apply1(const float* __restrict__ x, const float* __restrict__ sb,
                         u16* __restrict__ xb, int n4) {
  int i = blockIdx.x * 256 + threadIdx.x;
  if (i >= n4) return;
  const int cg = i & 15;
  float4 v = reinterpret_cast<const float4*>(x)[i];
  const float4 sc = reinterpret_cast<const float4*>(sb)[cg];
  const float4 bi = reinterpret_cast<const float4*>(sb)[16 + cg];
  float y0 = fmaxf(0.f, v.x * sc.x + bi.x);
  float y1 = fmaxf(0.f, v.y * sc.y + bi.y);
  float y2 = fmaxf(0.f, v.z * sc.z + bi.z);
  float y3 = fmaxf(0.f, v.w * sc.w + bi.w);
  ushort4 o;
  o.x = f2bf(y0); o.y = f2bf(y1); o.z = f2bf(y2); o.w = f2bf(y3);
  reinterpret_cast<ushort4*>(xb)[i] = o;
}

// out = x_net + relu(x*sc+bi)   (in-place on conv2 raw output)
__global__ void k_apply2(float* __restrict__ io, const float* __restrict__ sb,
                         const u16* __restrict__ xb, int n4) {
  int i = blockIdx.x * 256 + threadIdx.x;
  if (i >= n4) return;
  const int cg = i & 15;
  float4 v = reinterpret_cast<const float4*>(io)[i];
  const float4 sc = reinterpret_cast<const float4*>(sb)[cg];
  const float4 bi = reinterpret_cast<const float4*>(sb)[16 + cg];
  const ushort4 xn = reinterpret_cast<const ushort4*>(xb)[i];
  float4 o;
  o.x = bf2f(xn.x) + fmaxf(0.f, v.x * sc.x + bi.x);
  o.y = bf2f(xn.y) + fmaxf(0.f, v.y * sc.y + bi.y);
  o.z = bf2f(xn.z) + fmaxf(0.f, v.z * sc.z + bi.z);
  o.w = bf2f(xn.w) + fmaxf(0.f, v.w * sc.w + bi.w);
  reinterpret_cast<float4*>(io)[i] = o;
}

// ---------------- host ----------------

extern "C" void kernel_launch(void* const* d_in, const int* in_sizes, int n_in,
                              void* d_out, int out_size, void* d_ws, size_t ws_size,
                              hipStream_t stream) {
  const float* feats = (const float*)d_in[0];
  const float* W1 = (const float*)d_in[1];
  const float* g1 = (const float*)d_in[2];
  const float* b1 = (const float*)d_in[3];
  const float* W2 = (const float*)d_in[4];
  const float* g2 = (const float*)d_in[5];
  const float* b2 = (const float*)d_in[6];
  const int* nbr = (const int*)d_in[7];
  const int N = in_sizes[0] / 64;
  const int G = (N + 63) / 64;  // 64-voxel groups

  char* ws = (char*)d_ws;
  size_t off = 0;
  auto alloc = [&](size_t bytes) {
    void* p = ws + off;
    off = (off + bytes + 255) & ~(size_t)255;
    return p;
  };
  u16* featsb = (u16*)alloc((size_t)N * 64 * 2);
  u16* xnetb = (u16*)alloc((size_t)N * 64 * 2);
  u16* w1p = (u16*)alloc((size_t)KOFF * 4096 * 2);
  u16* w2p = (u16*)alloc((size_t)KOFF * 4096 * 2);
  float* stats = (float*)alloc(256 * 4);  // [s1 q1 s2 q2] x 64
  float* sb1 = (float*)alloc(128 * 4);
  float* sb2 = (float*)alloc(128 * 4);
  int4* nbrP = (int4*)alloc((size_t)(KOFF + 1) * G * 16 * 16);
  float* outf = (float*)d_out;

  const int n4 = N * 16;
  const int gPrep = (n4 + 255) / 256;
  const int gW = (KOFF * 4096 + 255) / 256;
  const int gConv = (G + 3) / 4;

  k_prep<<<G + 2 * gW + gPrep, 256, 0, stream>>>(feats, W1, W2, nbr, featsb, w1p, w2p,
                                                 nbrP, stats, N, G, gW, n4);

  k_conv<<<gConv, 256, 0, stream>>>(featsb, w1p, nbrP, outf, stats, N, G);
  k_final<<<1, 64, 0, stream>>>(stats, g1, b1, sb1, N);
  k_apply1<<<gPrep, 256, 0, stream>>>(outf, sb1, xnetb, n4);

  k_conv<<<gConv, 256, 0, stream>>>(xnetb, w2p, nbrP, outf, stats + 128, N, G);
  k_final<<<1, 64, 0, stream>>>(stats + 128, g2, b2, sb2, N);
  k_apply2<<<gPrep, 256, 0, stream>>>(outf, sb2, xnetb, n4);
}

// Round 9
// 374.313 us; speedup vs baseline: 2.0478x; 2.0478x over previous
//
#include <hip/hip_runtime.h>
#include <cstdint>
#include <cstddef>

typedef unsigned short u16;
typedef __bf16 bf16x8 __attribute__((ext_vector_type(8)));
typedef float f32x4 __attribute__((ext_vector_type(4)));

#define KOFF 27
#define EPSBN 1e-5f

__device__ inline u16 f2bf(float f) {
  unsigned int u = __float_as_uint(f);
  unsigned int r = (u + 0x7FFFu + ((u >> 16) & 1u)) >> 16;  // RNE
  return (u16)r;
}
__device__ inline float bf2f(u16 h) {
  return __uint_as_float(((unsigned int)h) << 16);
}

// ---------------- fused prep kernel ----------------
// blocks [0,G): pack neighbor table into per-wave int4 layout
//   nbrP[(k*G + g)*16 + l] = int4{ nbr[g*64+l][k], nbr[g*64+l+16][k],
//                                  nbr[g*64+l+32][k], nbr[g*64+l+48][k] }
//   plane k=27 = all -1 (padding so the k+1 prefetch at k=26 stays in-bounds).
// blocks [G, G+gW): pack W1 into MFMA B-frag order (bf16)
// blocks [G+gW, G+2gW): pack W2
// blocks [G+2gW, ...): cast feats->bf16 (first block also zeroes stats[256])
__global__ void k_prep(const float* __restrict__ feats, const float* __restrict__ W1,
                       const float* __restrict__ W2, const int* __restrict__ nbr,
                       u16* __restrict__ featsb, u16* __restrict__ w1p,
                       u16* __restrict__ w2p, int4* __restrict__ nbrP,
                       float* __restrict__ stats, int N, int G, int gW, int n4) {
  __shared__ int L[64 * KOFF];
  const int t = threadIdx.x;
  const int bid = blockIdx.x;

  if (bid < G) {  // neighbor pack
    const int g = bid;
    const int v0 = g * 64;
    for (int i = t; i < 64 * KOFF; i += 256) {
      const int v = v0 + i / KOFF;
      L[i] = (v < N) ? nbr[(size_t)v * KOFF + i % KOFF] : -1;
    }
    __syncthreads();
    for (int i = t; i < KOFF * 16; i += 256) {
      const int k = i >> 4, l = i & 15;
      int4 val;
      val.x = L[l * KOFF + k];
      val.y = L[(l + 16) * KOFF + k];
      val.z = L[(l + 32) * KOFF + k];
      val.w = L[(l + 48) * KOFF + k];
      nbrP[((size_t)k * G + g) * 16 + l] = val;
    }
    if (t < 16) nbrP[((size_t)KOFF * G + g) * 16 + t] = make_int4(-1, -1, -1, -1);
    return;
  }
  if (bid < G + 2 * gW) {  // weight pack
    const int wi = bid - G;
    const bool second = wi >= gW;
    const float* W = second ? W2 : W1;
    u16* Wp = second ? w2p : w1p;
    const int tid = (second ? wi - gW : wi) * 256 + t;
    if (tid >= KOFF * 4096) return;
    const int k = tid >> 12;
    const int rem = tid & 4095;
    const int slot = rem >> 3;
    const int e = rem & 7;
    const int ks = slot >> 8;
    const int ct = (slot >> 6) & 3;
    const int lane = slot & 63;
    const int j = ks * 32 + ((lane >> 4) << 3) + e;
    const int c = ct * 16 + (lane & 15);
    Wp[tid] = f2bf(W[(k * 64 + j) * 64 + c]);
    return;
  }
  // feats cast
  const int idx = bid - G - 2 * gW;
  if (idx == 0) stats[t] = 0.f;
  const int i = idx * 256 + t;
  if (i >= n4) return;
  const float4 v = reinterpret_cast<const float4*>(feats)[i];
  ushort4 o;
  o.x = f2bf(v.x); o.y = f2bf(v.y); o.z = f2bf(v.z); o.w = f2bf(v.w);
  reinterpret_cast<ushort4*>(featsb)[i] = o;
}

// ---------------- conv kernel (R2 structure, verified deltas only) ----------------
// Block 256 = 4 waves; each wave owns 64 voxels (group g) x all 64 out channels.
// Barrier-free, compiler-scheduled main loop (best measured structure, R2=95us).
// launch_bounds(256,3): the 64-voxel tile needs ~150 regs/wave (acc 64 AGPR +
// A 32 + B 32 + addr) — forcing 4 waves/SIMD (R8) spilled to scratch (+600MB
// traffic, 3.4x slower). 3 waves/SIMD is this tile's occupancy ceiling.
// Deltas vs R2: XCD swizzle (FETCH-verified), int4-packed neighbor ids.
// NO setprio, NO refill interleave, NO barriers (all measured regressions).
__launch_bounds__(256, 3)
__global__ void k_conv(const u16* __restrict__ F, const u16* __restrict__ Wp,
                       const int4* __restrict__ nbrP, float* __restrict__ out,
                       float* __restrict__ stats, int N, int G) {
  __shared__ float sred[4][128];
  const int t = threadIdx.x;
  const int w = t >> 6;
  const int lane = t & 63;

  // bijective XCD-aware block swizzle (m204 form)
  const int nwg = gridDim.x, bid = blockIdx.x;
  const int q = nwg >> 3, r = nwg & 7;
  const int xcd = bid & 7, o = bid >> 3;
  const int wg = (xcd < r ? xcd * (q + 1) : r * (q + 1) + (xcd - r) * q) + o;

  const int g = wg * 4 + w;              // this wave's 64-voxel group
  const int ch = (lane >> 4) << 3;       // A-frag channel offset (u16 units)
  const size_t G16 = (size_t)G * 16;     // int4 stride per k-plane
  const int4* nb = nbrP + (size_t)g * 16 + (lane & 15);

  f32x4 acc[4][4];
#pragma unroll
  for (int m = 0; m < 4; ++m)
#pragma unroll
    for (int c = 0; c < 4; ++c) acc[m][c] = (f32x4){0.f, 0.f, 0.f, 0.f};

  int4 idv = nb[0];  // ids for k=0
  const u16* bp = Wp + (lane << 3);

#pragma unroll 3
  for (int k = 0; k < KOFF; ++k) {
    // B fragments for this k (broadcast across waves -> L1 hits)
    bf16x8 bfr[2][4];
#pragma unroll
    for (int ks = 0; ks < 2; ++ks)
#pragma unroll
      for (int c = 0; c < 4; ++c)
        bfr[ks][c] = *reinterpret_cast<const bf16x8*>(bp + ((size_t)k << 12) + (ks << 11) + (c << 9));

    // A fragments: direct register gather (guarded, zero-init)
    const int ids[4] = {idv.x, idv.y, idv.z, idv.w};
    bf16x8 a0[4], a1[4];
#pragma unroll
    for (int m = 0; m < 4; ++m) {
      a0[m] = (bf16x8){};
      a1[m] = (bf16x8){};
      if (ids[m] >= 0) {
        const u16* fr = F + ((size_t)(unsigned)ids[m] << 6) + ch;
        a0[m] = *reinterpret_cast<const bf16x8*>(fr);
        a1[m] = *reinterpret_cast<const bf16x8*>(fr + 32);
      }
    }

    // prefetch next k's ids: one dwordx4 (plane 27 = -1 padding)
    idv = nb[(size_t)(k + 1) * G16];

#pragma unroll
    for (int m = 0; m < 4; ++m)
#pragma unroll
      for (int c = 0; c < 4; ++c)
        acc[m][c] = __builtin_amdgcn_mfma_f32_16x16x32_bf16(a0[m], bfr[0][c], acc[m][c], 0, 0, 0);
#pragma unroll
    for (int m = 0; m < 4; ++m)
#pragma unroll
      for (int c = 0; c < 4; ++c)
        acc[m][c] = __builtin_amdgcn_mfma_f32_16x16x32_bf16(a1[m], bfr[1][c], acc[m][c], 0, 0, 0);
  }

  // ---- store f32 + fused BN-stat partial reduction ----
  const int row0 = g * 64 + ((lane >> 4) << 2);
#pragma unroll
  for (int m = 0; m < 4; ++m) {
#pragma unroll
    for (int c = 0; c < 4; ++c) {
      const int col = (c << 4) + (lane & 15);
#pragma unroll
      for (int e = 0; e < 4; ++e) {
        const int v = row0 + (m << 4) + e;
        if (v < N) out[((size_t)v << 6) + col] = acc[m][c][e];
      }
    }
  }

#pragma unroll
  for (int c = 0; c < 4; ++c) {
    float s = 0.f, qq = 0.f;
#pragma unroll
    for (int m = 0; m < 4; ++m)
#pragma unroll
      for (int e = 0; e < 4; ++e) {
        const float x = acc[m][c][e];  // OOB rows contribute exact 0
        s += x;
        qq += x * x;
      }
    s += __shfl_xor(s, 16, 64);
    s += __shfl_xor(s, 32, 64);
    qq += __shfl_xor(qq, 16, 64);
    qq += __shfl_xor(qq, 32, 64);
    if (lane < 16) {
      sred[w][(c << 4) + lane] = s;
      sred[w][64 + (c << 4) + lane] = qq;
    }
  }
  __syncthreads();
  if (t < 128) {
    const float tot = sred[0][t] + sred[1][t] + sred[2][t] + sred[3][t];
    atomicAdd(&stats[t], tot);
  }
}

// ---------------- BN finalize / apply ----------------

__global__ void k_final(const float* __restrict__ stats, const float* __restrict__ gamma,
                        const float* __restrict__ beta, float* __restrict__ sb, int N) {
  const int c = threadIdx.x;  // 64
  const float inv = 1.0f / (float)N;
  const float mu = stats[c] * inv;
  const float var = stats[64 + c] * inv - mu * mu;
  const float sc = gamma[c] * rsqrtf(var + EPSBN);
  sb[c] = sc;
  sb[64 + c] = beta[c] - mu * sc;
}

// y = relu(x*sc+bi) -> bf16 x_net
__global__ void k_apply1(const float* __restrict__ x, const float* __restrict__ sb,
                         u16* __restrict__ xb, int n4) {
  int i = blockIdx.x * 256 + threadIdx.x;
  if (i >= n4) return;
  const int cg = i & 15;
  float4 v = reinterpret_cast<const float4*>(x)[i];
  const float4 sc = reinterpret_cast<const float4*>(sb)[cg];
  const float4 bi = reinterpret_cast<const float4*>(sb)[16 + cg];
  float y0 = fmaxf(0.f, v.x * sc.x + bi.x);
  float y1 = fmaxf(0.f, v.y * sc.y + bi.y);
  float y2 = fmaxf(0.f, v.z * sc.z + bi.z);
  float y3 = fmaxf(0.f, v.w * sc.w + bi.w);
  ushort4 o;
  o.x = f2bf(y0); o.y = f2bf(y1); o.z = f2bf(y2); o.w = f2bf(y3);
  reinterpret_cast<ushort4*>(xb)[i] = o;
}

// out = x_net + relu(x*sc+bi)   (in-place on conv2 raw output)
__global__ void k_apply2(float* __restrict__ io, const float* __restrict__ sb,
                         const u16* __restrict__ xb, int n4) {
  int i = blockIdx.x * 256 + threadIdx.x;
  if (i >= n4) return;
  const int cg = i & 15;
  float4 v = reinterpret_cast<const float4*>(io)[i];
  const float4 sc = reinterpret_cast<const float4*>(sb)[cg];
  const float4 bi = reinterpret_cast<const float4*>(sb)[16 + cg];
  const ushort4 xn = reinterpret_cast<const ushort4*>(xb)[i];
  float4 o;
  o.x = bf2f(xn.x) + fmaxf(0.f, v.x * sc.x + bi.x);
  o.y = bf2f(xn.y) + fmaxf(0.f, v.y * sc.y + bi.y);
  o.z = bf2f(xn.z) + fmaxf(0.f, v.z * sc.z + bi.z);
  o.w = bf2f(xn.w) + fmaxf(0.f, v.w * sc.w + bi.w);
  reinterpret_cast<float4*>(io)[i] = o;
}

// ---------------- host ----------------

extern "C" void kernel_launch(void* const* d_in, const int* in_sizes, int n_in,
                              void* d_out, int out_size, void* d_ws, size_t ws_size,
                              hipStream_t stream) {
  const float* feats = (const float*)d_in[0];
  const float* W1 = (const float*)d_in[1];
  const float* g1 = (const float*)d_in[2];
  const float* b1 = (const float*)d_in[3];
  const float* W2 = (const float*)d_in[4];
  const float* g2 = (const float*)d_in[5];
  const float* b2 = (const float*)d_in[6];
  const int* nbr = (const int*)d_in[7];
  const int N = in_sizes[0] / 64;
  const int G = (N + 63) / 64;  // 64-voxel groups

  char* ws = (char*)d_ws;
  size_t off = 0;
  auto alloc = [&](size_t bytes) {
    void* p = ws + off;
    off = (off + bytes + 255) & ~(size_t)255;
    return p;
  };
  u16* featsb = (u16*)alloc((size_t)N * 64 * 2);
  u16* xnetb = (u16*)alloc((size_t)N * 64 * 2);
  u16* w1p = (u16*)alloc((size_t)KOFF * 4096 * 2);
  u16* w2p = (u16*)alloc((size_t)KOFF * 4096 * 2);
  float* stats = (float*)alloc(256 * 4);  // [s1 q1 s2 q2] x 64
  float* sb1 = (float*)alloc(128 * 4);
  float* sb2 = (float*)alloc(128 * 4);
  int4* nbrP = (int4*)alloc((size_t)(KOFF + 1) * G * 16 * 16);
  float* outf = (float*)d_out;

  const int n4 = N * 16;
  const int gPrep = (n4 + 255) / 256;
  const int gW = (KOFF * 4096 + 255) / 256;
  const int gConv = (G + 3) / 4;

  k_prep<<<G + 2 * gW + gPrep, 256, 0, stream>>>(feats, W1, W2, nbr, featsb, w1p, w2p,
                                                 nbrP, stats, N, G, gW, n4);

  k_conv<<<gConv, 256, 0, stream>>>(featsb, w1p, nbrP, outf, stats, N, G);
  k_final<<<1, 64, 0, stream>>>(stats, g1, b1, sb1, N);
  k_apply1<<<gPrep, 256, 0, stream>>>(outf, sb1, xnetb, n4);

  k_conv<<<gConv, 256, 0, stream>>>(xnetb, w2p, nbrP, outf, stats + 128, N, G);
  k_final<<<1, 64, 0, stream>>>(stats + 128, g2, b2, sb2, N);
  k_apply2<<<gPrep, 256, 0, stream>>>(outf, sb2, xnetb, n4);
}

// Round 10
// 259.019 us; speedup vs baseline: 2.9593x; 1.4451x over previous
//
#include <hip/hip_runtime.h>
#include <cstdint>
#include <cstddef>

typedef unsigned short u16;
typedef __bf16 bf16x8 __attribute__((ext_vector_type(8)));
typedef float f32x4 __attribute__((ext_vector_type(4)));

#define KOFF 27
#define EPSBN 1e-5f

__device__ inline u16 f2bf(float f) {
  unsigned int u = __float_as_uint(f);
  unsigned int r = (u + 0x7FFFu + ((u >> 16) & 1u)) >> 16;  // RNE
  return (u16)r;
}
__device__ inline float bf2f(u16 h) {
  return __uint_as_float(((unsigned int)h) << 16);
}

// ---------------- fused prep kernel ----------------
// blocks [0, gN): transpose nbr [N,27] -> nbrT [27,N] (R2 layout, coalesced)
// blocks [gN, gN+gW): pack W1 into MFMA B-frag order (bf16)
// blocks [gN+gW, gN+2gW): pack W2
// blocks [gN+2gW, ...): cast feats->bf16 (first block also zeroes stats[256])
__global__ void k_prep(const float* __restrict__ feats, const float* __restrict__ W1,
                       const float* __restrict__ W2, const int* __restrict__ nbr,
                       u16* __restrict__ featsb, u16* __restrict__ w1p,
                       u16* __restrict__ w2p, int* __restrict__ nbrT,
                       float* __restrict__ stats, int N, int gN, int gW, int n4) {
  __shared__ int L[64 * KOFF];
  const int t = threadIdx.x;
  const int bid = blockIdx.x;

  if (bid < gN) {  // neighbor transpose (R2's k_prep_nbrT logic)
    const int v0 = bid * 64;
    const int nv = min(64, N - v0);
    const int cnt = nv * KOFF;
    for (int i = t; i < cnt; i += 256) L[i] = nbr[(size_t)v0 * KOFF + i];
    __syncthreads();
    for (int i = t; i < KOFF * 64; i += 256) {
      int k = i >> 6, j = i & 63;
      if (j < nv) nbrT[(size_t)k * N + v0 + j] = L[j * KOFF + k];
    }
    return;
  }
  if (bid < gN + 2 * gW) {  // weight pack
    const int wi = bid - gN;
    const bool second = wi >= gW;
    const float* W = second ? W2 : W1;
    u16* Wp = second ? w2p : w1p;
    const int tid = (second ? wi - gW : wi) * 256 + t;
    if (tid >= KOFF * 4096) return;
    const int k = tid >> 12;
    const int rem = tid & 4095;
    const int slot = rem >> 3;
    const int e = rem & 7;
    const int ks = slot >> 8;
    const int ct = (slot >> 6) & 3;
    const int lane = slot & 63;
    const int j = ks * 32 + ((lane >> 4) << 3) + e;
    const int c = ct * 16 + (lane & 15);
    Wp[tid] = f2bf(W[(k * 64 + j) * 64 + c]);
    return;
  }
  // feats cast
  const int idx = bid - gN - 2 * gW;
  if (idx == 0) stats[t] = 0.f;
  const int i = idx * 256 + t;
  if (i >= n4) return;
  const float4 v = reinterpret_cast<const float4*>(feats)[i];
  ushort4 o;
  o.x = f2bf(v.x); o.y = f2bf(v.y); o.z = f2bf(v.z); o.w = f2bf(v.w);
  reinterpret_cast<ushort4*>(featsb)[i] = o;
}

// ---------------- conv kernel (verbatim R2 — best measured: 95us, Mfma 27.5%) ----------------
// Block 256 = 4 waves; each wave owns 64 voxels x all 64 output channels.
// A-fragments gathered straight from global (16B/lane, frag-layout-native);
// B-fragments read straight from global (pre-packed, L1/L2-resident).
// Neighbor indices for k+1 prefetched (4 scalar loads). No barriers, no swizzle,
// no int4 pack (R9 bisect: {int4+swizzle} package = +55us on this body).
// Epilogue fuses the BN batch-stat partial reduction (atomicAdd into stats[128]).
__launch_bounds__(256, 3)
__global__ void k_conv(const u16* __restrict__ F, const u16* __restrict__ Wp,
                       const int* __restrict__ nbrT, float* __restrict__ out,
                       float* __restrict__ stats, int N) {
  const int t = threadIdx.x;
  const int w = t >> 6;
  const int lane = t & 63;
  const int vbase = blockIdx.x * 256 + (w << 6) + (lane & 15);
  const int ch = (lane >> 4) << 3;  // A-frag channel offset (elements)

  f32x4 acc[4][4];
#pragma unroll
  for (int m = 0; m < 4; ++m)
#pragma unroll
    for (int c = 0; c < 4; ++c) acc[m][c] = (f32x4){0.f, 0.f, 0.f, 0.f};

  // prefetch k=0 neighbor indices
  int nid[4];
#pragma unroll
  for (int m = 0; m < 4; ++m) {
    const int v = vbase + (m << 4);
    nid[m] = (v < N) ? nbrT[v] : -1;
  }

  const u16* bp = Wp + ((size_t)lane << 3);

#pragma unroll 3
  for (int k = 0; k < KOFF; ++k) {
    // B fragments for this k (broadcast across waves -> L1/L2 hits)
    bf16x8 bfr[2][4];
#pragma unroll
    for (int ks = 0; ks < 2; ++ks)
#pragma unroll
      for (int c = 0; c < 4; ++c)
        bfr[ks][c] = *reinterpret_cast<const bf16x8*>(bp + ((size_t)k << 12) + (ks << 11) + (c << 9));

    // A fragments: direct register gather
    bf16x8 a0[4], a1[4];
#pragma unroll
    for (int m = 0; m < 4; ++m) {
      a0[m] = (bf16x8){};
      a1[m] = (bf16x8){};
      const int id = nid[m];
      if (id >= 0) {
        const u16* fr = F + ((size_t)id << 6) + ch;
        a0[m] = *reinterpret_cast<const bf16x8*>(fr);
        a1[m] = *reinterpret_cast<const bf16x8*>(fr + 32);
      }
    }

    // prefetch next k's indices (latency hidden under the MFMA block)
    if (k + 1 < KOFF) {
      const int* nk = nbrT + (size_t)(k + 1) * N;
#pragma unroll
      for (int m = 0; m < 4; ++m) {
        const int v = vbase + (m << 4);
        nid[m] = (v < N) ? nk[v] : -1;
      }
    }

#pragma unroll
    for (int m = 0; m < 4; ++m)
#pragma unroll
      for (int c = 0; c < 4; ++c)
        acc[m][c] = __builtin_amdgcn_mfma_f32_16x16x32_bf16(a0[m], bfr[0][c], acc[m][c], 0, 0, 0);
#pragma unroll
    for (int m = 0; m < 4; ++m)
#pragma unroll
      for (int c = 0; c < 4; ++c)
        acc[m][c] = __builtin_amdgcn_mfma_f32_16x16x32_bf16(a1[m], bfr[1][c], acc[m][c], 0, 0, 0);
  }

  // ---- store + fused BN-stat partial reduction ----
  const int row0 = blockIdx.x * 256 + (w << 6) + ((lane >> 4) << 2);
#pragma unroll
  for (int m = 0; m < 4; ++m) {
#pragma unroll
    for (int c = 0; c < 4; ++c) {
      const int col = (c << 4) + (lane & 15);
#pragma unroll
      for (int e = 0; e < 4; ++e) {
        const int v = row0 + (m << 4) + e;
        if (v < N) out[((size_t)v << 6) + col] = acc[m][c][e];
      }
    }
  }

  __shared__ float sred[4][128];
#pragma unroll
  for (int c = 0; c < 4; ++c) {
    float s = 0.f, q = 0.f;
#pragma unroll
    for (int m = 0; m < 4; ++m)
#pragma unroll
      for (int e = 0; e < 4; ++e) {
        const float x = acc[m][c][e];  // OOB rows contribute exact 0
        s += x;
        q += x * x;
      }
    s += __shfl_xor(s, 16, 64);
    s += __shfl_xor(s, 32, 64);
    q += __shfl_xor(q, 16, 64);
    q += __shfl_xor(q, 32, 64);
    if (lane < 16) {
      sred[w][(c << 4) + lane] = s;
      sred[w][64 + (c << 4) + lane] = q;
    }
  }
  __syncthreads();
  if (t < 128) {
    const float tot = sred[0][t] + sred[1][t] + sred[2][t] + sred[3][t];
    atomicAdd(&stats[t], tot);
  }
}

// ---------------- BN finalize / apply ----------------

__global__ void k_final(const float* __restrict__ stats, const float* __restrict__ gamma,
                        const float* __restrict__ beta, float* __restrict__ sb, int N) {
  const int c = threadIdx.x;  // 64
  const float inv = 1.0f / (float)N;
  const float mu = stats[c] * inv;
  const float var = stats[64 + c] * inv - mu * mu;
  const float sc = gamma[c] * rsqrtf(var + EPSBN);
  sb[c] = sc;
  sb[64 + c] = beta[c] - mu * sc;
}

// y = relu(x*sc+bi) -> bf16 x_net
__global__ void k_apply1(const float* __restrict__ x, const float* __restrict__ sb,
                         u16* __restrict__ xb, int n4) {
  int i = blockIdx.x * 256 + threadIdx.x;
  if (i >= n4) return;
  const int cg = i & 15;
  float4 v = reinterpret_cast<const float4*>(x)[i];
  const float4 sc = reinterpret_cast<const float4*>(sb)[cg];
  const float4 bi = reinterpret_cast<const float4*>(sb)[16 + cg];
  float y0 = fmaxf(0.f, v.x * sc.x + bi.x);
  float y1 = fmaxf(0.f, v.y * sc.y + bi.y);
  float y2 = fmaxf(0.f, v.z * sc.z + bi.z);
  float y3 = fmaxf(0.f, v.w * sc.w + bi.w);
  ushort4 o;
  o.x = f2bf(y0); o.y = f2bf(y1); o.z = f2bf(y2); o.w = f2bf(y3);
  reinterpret_cast<ushort4*>(xb)[i] = o;
}

// out = x_net + relu(x*sc+bi)   (in-place on conv2 raw output)
__global__ void k_apply2(float* __restrict__ io, const float* __restrict__ sb,
                         const u16* __restrict__ xb, int n4) {
  int i = blockIdx.x * 256 + threadIdx.x;
  if (i >= n4) return;
  const int cg = i & 15;
  float4 v = reinterpret_cast<const float4*>(io)[i];
  const float4 sc = reinterpret_cast<const float4*>(sb)[cg];
  const float4 bi = reinterpret_cast<const float4*>(sb)[16 + cg];
  const ushort4 xn = reinterpret_cast<const ushort4*>(xb)[i];
  float4 o;
  o.x = bf2f(xn.x) + fmaxf(0.f, v.x * sc.x + bi.x);
  o.y = bf2f(xn.y) + fmaxf(0.f, v.y * sc.y + bi.y);
  o.z = bf2f(xn.z) + fmaxf(0.f, v.z * sc.z + bi.z);
  o.w = bf2f(xn.w) + fmaxf(0.f, v.w * sc.w + bi.w);
  reinterpret_cast<float4*>(io)[i] = o;
}

// ---------------- host ----------------

extern "C" void kernel_launch(void* const* d_in, const int* in_sizes, int n_in,
                              void* d_out, int out_size, void* d_ws, size_t ws_size,
                              hipStream_t stream) {
  const float* feats = (const float*)d_in[0];
  const float* W1 = (const float*)d_in[1];
  const float* g1 = (const float*)d_in[2];
  const float* b1 = (const float*)d_in[3];
  const float* W2 = (const float*)d_in[4];
  const float* g2 = (const float*)d_in[5];
  const float* b2 = (const float*)d_in[6];
  const int* nbr = (const int*)d_in[7];
  const int N = in_sizes[0] / 64;

  char* ws = (char*)d_ws;
  size_t off = 0;
  auto alloc = [&](size_t bytes) {
    void* p = ws + off;
    off = (off + bytes + 255) & ~(size_t)255;
    return p;
  };
  u16* featsb = (u16*)alloc((size_t)N * 64 * 2);
  u16* xnetb = (u16*)alloc((size_t)N * 64 * 2);
  u16* w1p = (u16*)alloc((size_t)KOFF * 4096 * 2);
  u16* w2p = (u16*)alloc((size_t)KOFF * 4096 * 2);
  float* stats = (float*)alloc(256 * 4);  // [s1 q1 s2 q2] x 64
  float* sb1 = (float*)alloc(128 * 4);
  float* sb2 = (float*)alloc(128 * 4);
  int* nbrT = (int*)alloc((size_t)KOFF * N * 4);
  float* outf = (float*)d_out;

  const int n4 = N * 16;
  const int gN = (N + 63) / 64;
  const int gPrep = (n4 + 255) / 256;
  const int gW = (KOFF * 4096 + 255) / 256;
  const int gConv = (N + 255) / 256;

  k_prep<<<gN + 2 * gW + gPrep, 256, 0, stream>>>(feats, W1, W2, nbr, featsb, w1p, w2p,
                                                  nbrT, stats, N, gN, gW, n4);

  k_conv<<<gConv, 256, 0, stream>>>(featsb, w1p, nbrT, outf, stats, N);
  k_final<<<1, 64, 0, stream>>>(stats, g1, b1, sb1, N);
  k_apply1<<<gPrep, 256, 0, stream>>>(outf, sb1, xnetb, n4);

  k_conv<<<gConv, 256, 0, stream>>>(xnetb, w2p, nbrT, outf, stats + 128, N);
  k_final<<<1, 64, 0, stream>>>(stats + 128, g2, b2, sb2, N);
  k_apply2<<<gPrep, 256, 0, stream>>>(outf, sb2, xnetb, n4);
}